// Round 21
// baseline (188.734 us; speedup 1.0000x reference)
//
#include <hip/hip_runtime.h>
#include <hip/hip_fp16.h>

// GCN: atomic-free two-level CSR build + split layer-1 (standalone gather-agg
// at fabric floor + high-occupancy fused MFMA GEMM1+GEMM2) + agg2.
//   1) k_prep: per-chunk bucket hist -> counts[chunk][bucket] + W1t/W2t cvt
//   2) k_colscan: per-bucket exclusive prefix over chunks (in-place) + totals
//   3) k_scatter2: local scan of btot -> bstart (block 0 publishes); LDS cursors
//      = bstart+cbase; LDS-atomic rank; X->fp16 convert tail
//   4) k_sort: per-bucket LDS counting sort -> edge_src (dst-sorted), row_start
//   5) k_agg1: agg1h[n] = fp16((1/deg) * sum X16[src])  (16 lanes/node, 8-deep)
//   6) k_mgemm2: m2h = fp16( relu(agg1h@W1+b1) @ W2 )   (fused, barrier-fenced)
//   7) k_agg2: out[n] = (1/deg) * sum m2h[src] + b2     (8 lanes/node, 16 deep)
// Requires N <= 2^17. N = 100000 here.

constexpr int CAP = 3072;      // max edges/bucket on LDS sort fast path
constexpr int CHUNK = 8192;    // edges per scatter chunk

typedef _Float16 f16x8 __attribute__((ext_vector_type(8)));
typedef float f32x4 __attribute__((ext_vector_type(4)));

// blocks < NC: hist of chunk -> counts[c][b] (coalesced store, no atomics)
// blocks NC..NC+95: W transposes.
__global__ __launch_bounds__(256) void k_prep(
    const int* __restrict__ dst, int* __restrict__ counts,
    const float* __restrict__ W1, const float* __restrict__ W2,
    __half* __restrict__ W1t, __half* __restrict__ W2t,
    int E, int NB, int NC)
{
    __shared__ int sh[1024];
    const int tid = threadIdx.x;
    if (blockIdx.x < NC) {
        const int c = blockIdx.x;
        const int b0 = c * CHUNK;
        const int cnt = min(CHUNK, E - b0);
        for (int i = tid; i < NB; i += 256) sh[i] = 0;
        __syncthreads();
        for (int i = tid; i < cnt; i += 256)
            atomicAdd(&sh[dst[b0 + i] >> 7], 1);
        __syncthreads();
        for (int i = tid; i < NB; i += 256) counts[(size_t)c * NB + i] = sh[i];
    } else {
        const int t = (blockIdx.x - NC) * 256 + tid;   // < 24576 exactly
        if (t < 128 * 128) {
            const int k = t >> 7, n = t & 127;
            W1t[n * 128 + k] = __float2half(W1[t]);
        } else {
            const int u = t - 128 * 128;
            const int k = u >> 6, n = u & 63;
            W2t[n * 128 + k] = __float2half(W2[u]);
        }
    }
}

// One block per bucket: exclusive prefix of counts[*][b] over chunks (in-place),
// totals -> btot[b].
__global__ __launch_bounds__(256) void k_colscan(
    int* __restrict__ counts, int* __restrict__ btot, int NB, int NC)
{
    __shared__ int sh[256];
    const int b = blockIdx.x;
    const int tid = threadIdx.x;
    int carry = 0;
    for (int t0 = 0; t0 < NC; t0 += 256) {
        const int idx = t0 + tid;
        const int v = (idx < NC) ? counts[(size_t)idx * NB + b] : 0;
        sh[tid] = v;
        __syncthreads();
        for (int off = 1; off < 256; off <<= 1) {
            int u = (tid >= off) ? sh[tid - off] : 0;
            __syncthreads();
            if (tid >= off) sh[tid] += u;
            __syncthreads();
        }
        const int incl = sh[tid];
        const int tile_total = sh[255];
        if (idx < NC) counts[(size_t)idx * NB + b] = incl - v + carry;
        carry += tile_total;
        __syncthreads();   // sh reused next tile
    }
    if (tid == 0) btot[b] = carry;
}

// Blocks < NC: local exclusive scan of btot -> bstartL (block 0 publishes to
// global bstart for k_sort); cursors = bstartL + cbase; LDS-atomic rank;
// scatter into block-private bucket windows. ALL blocks: X->fp16 convert tail.
__global__ __launch_bounds__(256) void k_scatter2(
    const int* __restrict__ src, const int* __restrict__ dst,
    const int* __restrict__ cbase, const int* __restrict__ btot,
    int* __restrict__ bstart_out, unsigned* __restrict__ pairs,
    const float* __restrict__ X, __half* __restrict__ X16,
    int E, int NB, int NC, long long n4)
{
    __shared__ int cur[1024];
    __shared__ int part[256];
    const int c = blockIdx.x;
    const int tid = threadIdx.x;

    if (c < NC) {
        // local exclusive scan of btot[0..NB) into cur[0..1023]
        int v[4];
        int run = 0;
#pragma unroll
        for (int q = 0; q < 4; ++q) {
            const int idx = tid * 4 + q;
            const int t = (idx < NB) ? btot[idx] : 0;
            v[q] = run;
            run += t;
        }
        part[tid] = run;
        __syncthreads();
        for (int off = 1; off < 256; off <<= 1) {
            int u = (tid >= off) ? part[tid - off] : 0;
            __syncthreads();
            if (tid >= off) part[tid] += u;
            __syncthreads();
        }
        const int excl = part[tid] - run;
#pragma unroll
        for (int q = 0; q < 4; ++q) cur[tid * 4 + q] = v[q] + excl;
        __syncthreads();

        if (c == 0) {
            for (int i = tid; i < NB; i += 256) bstart_out[i] = cur[i];
            if (tid == 0) bstart_out[NB] = E;
        }

        // cursors = bstartL + per-chunk base
        for (int i = tid; i < NB; i += 256)
            cur[i] += cbase[(size_t)c * NB + i];
        __syncthreads();

        const int b0 = c * CHUNK;
        const int cnt = min(CHUNK, E - b0);
        int i = tid;
        for (; i + 768 < cnt; i += 1024) {
            const int d0 = dst[b0 + i], s0 = src[b0 + i];
            const int d1 = dst[b0 + i + 256], s1 = src[b0 + i + 256];
            const int d2 = dst[b0 + i + 512], s2 = src[b0 + i + 512];
            const int d3 = dst[b0 + i + 768], s3 = src[b0 + i + 768];
            const int p0 = atomicAdd(&cur[d0 >> 7], 1);
            const int p1 = atomicAdd(&cur[d1 >> 7], 1);
            const int p2 = atomicAdd(&cur[d2 >> 7], 1);
            const int p3 = atomicAdd(&cur[d3 >> 7], 1);
            pairs[p0] = (unsigned)s0 | ((unsigned)(d0 & 127) << 17);
            pairs[p1] = (unsigned)s1 | ((unsigned)(d1 & 127) << 17);
            pairs[p2] = (unsigned)s2 | ((unsigned)(d2 & 127) << 17);
            pairs[p3] = (unsigned)s3 | ((unsigned)(d3 & 127) << 17);
        }
        for (; i < cnt; i += 256) {
            const int d = dst[b0 + i];
            const int p = atomicAdd(&cur[d >> 7], 1);
            pairs[p] = (unsigned)src[b0 + i] | ((unsigned)(d & 127) << 17);
        }
    }

    // X -> fp16 convert tail (all blocks). Consumed by k_agg1 (after k_sort).
    for (long long i = (long long)blockIdx.x * 256 + tid; i < n4;
         i += (long long)gridDim.x * 256) {
        const float4 v = ((const float4*)X)[i];
        __half2 h0 = __floats2half2_rn(v.x, v.y);
        __half2 h1 = __floats2half2_rn(v.z, v.w);
        uint2 o;
        o.x = *(const unsigned*)&h0;
        o.y = *(const unsigned*)&h1;
        ((uint2*)X16)[i] = o;
    }
}

__global__ __launch_bounds__(256) void k_sort(
    const unsigned* __restrict__ pairs, const int* __restrict__ bstart,
    int* __restrict__ edge_src, int* __restrict__ row_start, int N, int E)
{
    __shared__ unsigned sp[CAP];
    __shared__ int sorted[CAP];
    __shared__ int lcnt[128];
    __shared__ int ls[128];
    const int b = blockIdx.x;
    const int tid = threadIdx.x;
    const int beg = bstart[b], end = bstart[b + 1];
    const int cnt = end - beg;
    const bool fits = (cnt <= CAP);

    if (tid < 128) lcnt[tid] = 0;
    __syncthreads();

    if (fits) {
        for (int i = tid; i < cnt; i += 256) {
            const unsigned p = pairs[beg + i];
            sp[i] = p;
            atomicAdd(&lcnt[p >> 17], 1);
        }
    } else {
        for (int i = tid; i < cnt; i += 256)
            atomicAdd(&lcnt[pairs[beg + i] >> 17], 1);
    }
    __syncthreads();

    if (tid < 128) ls[tid] = lcnt[tid];
    __syncthreads();
    for (int off = 1; off < 128; off <<= 1) {
        int v = 0;
        if (tid < 128 && tid >= off) v = ls[tid - off];
        __syncthreads();
        if (tid < 128 && tid >= off) ls[tid] += v;
        __syncthreads();
    }

    if (tid < 128) {
        const int node = b * 128 + tid;
        if (node <= N) row_start[node] = beg + ls[tid] - lcnt[tid];
    }
    if (b == 0 && tid == 0) row_start[N] = E;
    __syncthreads();

    if (tid < 128) ls[tid] -= lcnt[tid];
    __syncthreads();

    if (fits) {
        for (int i = tid; i < cnt; i += 256) {
            const unsigned p = sp[i];
            const int pos = atomicAdd(&ls[p >> 17], 1);
            sorted[pos] = (int)(p & 0x1FFFFu);
        }
        __syncthreads();
        for (int i = tid; i < cnt; i += 256) edge_src[beg + i] = sorted[i];
    } else {
        for (int i = tid; i < cnt; i += 256) {
            const unsigned p = pairs[beg + i];
            const int pos = atomicAdd(&ls[p >> 17], 1);
            edge_src[beg + pos] = (int)(p & 0x1FFFFu);
        }
    }
}

// Layer-1 agg (R13-proven): 16 lanes per node (4 nodes/wave), 8 gathers in
// flight, f32 acc, fp16 out with 1/deg folded.
__global__ __launch_bounds__(256) void k_agg1(
    const __half* __restrict__ M, const int* __restrict__ edge_src,
    const int* __restrict__ row_start, __half* __restrict__ outp, int N)
{
    const int node = (blockIdx.x * 256 + threadIdx.x) >> 4;
    if (node >= N) return;
    const unsigned li = threadIdx.x & 15;
    const int beg = row_start[node];
    const int end = row_start[node + 1];
    const float inv = 1.0f / fmaxf((float)(end - beg), 1.0f);
    const uint4* M4 = (const uint4*)M;   // 16 uint4 per row

    float acc[8] = {};
    int j = beg;
    for (; j + 7 < end; j += 8) {
        unsigned o[8];
#pragma unroll
        for (int q = 0; q < 8; ++q)
            o[q] = ((unsigned)edge_src[j + q] << 4) | li;
        uint4 v[8];
#pragma unroll
        for (int q = 0; q < 8; ++q) v[q] = M4[o[q]];
#pragma unroll
        for (int q = 0; q < 8; ++q) {
            const __half2* h = (const __half2*)&v[q];
#pragma unroll
            for (int p = 0; p < 4; ++p) {
                const float2 f = __half22float2(h[p]);
                acc[2 * p] += f.x;
                acc[2 * p + 1] += f.y;
            }
        }
    }
    for (; j < end; ++j) {
        const uint4 v = M4[((unsigned)edge_src[j] << 4) | li];
        const __half2* h = (const __half2*)&v;
#pragma unroll
        for (int p = 0; p < 4; ++p) {
            const float2 f = __half22float2(h[p]);
            acc[2 * p] += f.x;
            acc[2 * p + 1] += f.y;
        }
    }
    __half2 r[4];
#pragma unroll
    for (int p = 0; p < 4; ++p)
        r[p] = __floats2half2_rn(acc[2 * p] * inv, acc[2 * p + 1] * inv);
    ((uint4*)(outp + (size_t)node * 128))[li] = *(const uint4*)r;
}

// Fused MFMA GEMM (R15-proven): m2h = fp16( relu(A@W1 + b1) @ W2 ),
// 64 rows/block, 4 waves, A from global. All LDS phase crossings fenced.
__global__ __launch_bounds__(256) void k_mgemm2(
    const __half* __restrict__ A, const __half* __restrict__ W1t,
    const float* __restrict__ b1, const __half* __restrict__ W2t,
    __half* __restrict__ C, int N)
{
    __shared__ __align__(16) char lds[16384];
    const int tid = threadIdx.x;
    const int row0 = blockIdx.x * 64;

    // phase 1: stage A tile (64 x 128 fp16), XOR-swizzled rows
    for (int i = tid; i < 1024; i += 256) {
        const int r = i >> 4, ch = i & 15;
        const int row = row0 + r;
        uint4 v = make_uint4(0, 0, 0, 0);
        if (row < N) v = *(const uint4*)(A + (size_t)row * 128 + ch * 8);
        *(uint4*)(lds + r * 256 + ((ch * 16) ^ ((r & 7) << 4))) = v;
    }
    __syncthreads();

    const int w = tid >> 6, l = tid & 63;
    const int lr = l & 15, lk = l >> 4;
    const int arow = w * 16 + lr;

    // phase 2: GEMM1
    f32x4 acc1[8] = {};
#pragma unroll
    for (int kb = 0; kb < 4; ++kb) {
        const f16x8 a = *(const f16x8*)(lds + arow * 256 +
                                        ((kb * 64 + lk * 16) ^ ((arow & 7) << 4)));
#pragma unroll
        for (int nt = 0; nt < 8; ++nt) {
            const f16x8 b = *(const f16x8*)(W1t + (nt * 16 + lr) * 128 + kb * 32 + lk * 8);
            acc1[nt] = __builtin_amdgcn_mfma_f32_16x16x32_f16(a, b, acc1[nt], 0, 0, 0);
        }
    }
    __syncthreads();   // A-tile reads done (cross-wave staging)

    // phase 3: h tile (16 x 128 fp16, bias+relu) -> wave-private swizzled LDS
    char* hw = lds + w * 4096;
#pragma unroll
    for (int nt = 0; nt < 8; ++nt) {
        const int col = nt * 16 + lr;
        const float bv = b1[col];
#pragma unroll
        for (int i = 0; i < 4; ++i) {
            const int r = lk * 4 + i;
            const float v = fmaxf(acc1[nt][i] + bv, 0.f);
            *(__half*)(hw + r * 256 + ((col * 2) ^ ((r & 7) << 4))) = __float2half(v);
        }
    }
    __syncthreads();   // fence: h writes ordered before a2 reads

    // phase 4: GEMM2 from LDS h
    f32x4 acc2[4] = {};
#pragma unroll
    for (int kb = 0; kb < 4; ++kb) {
        const f16x8 a2 = *(const f16x8*)(hw + lr * 256 +
                                         ((kb * 64 + lk * 16) ^ ((lr & 7) << 4)));
#pragma unroll
        for (int nt = 0; nt < 4; ++nt) {
            const f16x8 b = *(const f16x8*)(W2t + (nt * 16 + lr) * 128 + kb * 32 + lk * 8);
            acc2[nt] = __builtin_amdgcn_mfma_f32_16x16x32_f16(a2, b, acc2[nt], 0, 0, 0);
        }
    }
    __syncthreads();   // fence: a2 reads done before m2 overwrites h region

    // phase 5: m2 tile (16 x 64 fp16) bounce in the same wave region
#pragma unroll
    for (int nt = 0; nt < 4; ++nt) {
        const int col = nt * 16 + lr;
#pragma unroll
        for (int i = 0; i < 4; ++i) {
            const int r = lk * 4 + i;
            *(__half*)(hw + r * 128 + ((col * 2) ^ ((r & 7) << 4))) = __float2half(acc2[nt][i]);
        }
    }
    __syncthreads();   // fence: m2 writes ordered before copy-out reads

    // phase 6: coalesced copy-out
    const int rbase = row0 + w * 16;
    for (int i = l; i < 128; i += 64) {
        const int r = i >> 3, c = i & 7;
        const int row = rbase + r;
        if (row < N)
            *(uint4*)(C + (size_t)row * 64 + c * 8) =
                *(const uint4*)(hw + r * 128 + ((c * 16) ^ ((r & 7) << 4)));
    }
}

// Layer-2 agg: 8 lanes per node (8 nodes/wave), 16 edges in flight per group.
// f32 out with 1/deg and bias fused.
__global__ __launch_bounds__(256) void k_agg2(
    const __half* __restrict__ M, const int* __restrict__ edge_src,
    const int* __restrict__ row_start, const float* __restrict__ bias,
    float* __restrict__ outp, int N)
{
    const int node = (blockIdx.x * 256 + threadIdx.x) >> 3;
    if (node >= N) return;
    const unsigned li = threadIdx.x & 7;
    const int beg = row_start[node];
    const int end = row_start[node + 1];
    const float inv = 1.0f / fmaxf((float)(end - beg), 1.0f);
    const uint4* M4 = (const uint4*)M;   // 8 uint4 per row

    float acc[8] = {};
    int j = beg;
    for (; j + 15 < end; j += 16) {
        unsigned o[16];
#pragma unroll
        for (int q = 0; q < 16; ++q)
            o[q] = ((unsigned)edge_src[j + q] << 3) | li;
        uint4 v[16];
#pragma unroll
        for (int q = 0; q < 16; ++q) v[q] = M4[o[q]];
#pragma unroll
        for (int q = 0; q < 16; ++q) {
            const __half2* h = (const __half2*)&v[q];
#pragma unroll
            for (int p = 0; p < 4; ++p) {
                const float2 f = __half22float2(h[p]);
                acc[2 * p] += f.x;
                acc[2 * p + 1] += f.y;
            }
        }
    }
    for (; j + 3 < end; j += 4) {
        unsigned o[4];
#pragma unroll
        for (int q = 0; q < 4; ++q)
            o[q] = ((unsigned)edge_src[j + q] << 3) | li;
        uint4 v[4];
#pragma unroll
        for (int q = 0; q < 4; ++q) v[q] = M4[o[q]];
#pragma unroll
        for (int q = 0; q < 4; ++q) {
            const __half2* h = (const __half2*)&v[q];
#pragma unroll
            for (int p = 0; p < 4; ++p) {
                const float2 f = __half22float2(h[p]);
                acc[2 * p] += f.x;
                acc[2 * p + 1] += f.y;
            }
        }
    }
    for (; j < end; ++j) {
        const uint4 v = M4[((unsigned)edge_src[j] << 3) | li];
        const __half2* h = (const __half2*)&v;
#pragma unroll
        for (int p = 0; p < 4; ++p) {
            const float2 f = __half22float2(h[p]);
            acc[2 * p] += f.x;
            acc[2 * p + 1] += f.y;
        }
    }
    const float4 b0 = ((const float4*)bias)[li * 2];
    const float4 b1 = ((const float4*)bias)[li * 2 + 1];
    float4 o0, o1;
    o0.x = fmaf(acc[0], inv, b0.x);
    o0.y = fmaf(acc[1], inv, b0.y);
    o0.z = fmaf(acc[2], inv, b0.z);
    o0.w = fmaf(acc[3], inv, b0.w);
    o1.x = fmaf(acc[4], inv, b1.x);
    o1.y = fmaf(acc[5], inv, b1.y);
    o1.z = fmaf(acc[6], inv, b1.z);
    o1.w = fmaf(acc[7], inv, b1.w);
    float4* op = (float4*)(outp + (size_t)node * 64);
    op[li * 2] = o0;
    op[li * 2 + 1] = o1;
}

extern "C" void kernel_launch(void* const* d_in, const int* in_sizes, int n_in,
                              void* d_out, int out_size, void* d_ws, size_t ws_size,
                              hipStream_t stream)
{
    const float* X  = (const float*)d_in[0];
    const int*  src = (const int*)d_in[1];
    const int*  dst = (const int*)d_in[2];
    const float* W1 = (const float*)d_in[3];
    const float* b1 = (const float*)d_in[4];
    const float* W2 = (const float*)d_in[5];
    const float* b2 = (const float*)d_in[6];
    float* out = (float*)d_out;

    const int N = in_sizes[0] / 128;
    const int E = in_sizes[1];
    const int NB = (N + 127) / 128;
    const int NC = (E + CHUNK - 1) / CHUNK;

    __half* X16    = (__half*)d_ws;                        // N*128 f16
    __half* agg1h  = X16 + (size_t)N * 128;                // N*128 f16
    __half* m2h    = agg1h + (size_t)N * 128;              // N*64 f16
    unsigned* pairs = (unsigned*)(m2h + (size_t)N * 64);   // E u32
    int* edge_src  = (int*)(pairs + E);                    // E
    int* row_start = edge_src + E;                         // N+1
    int* bstart    = row_start + N + 1;                    // NB+1
    int* btot      = bstart + NB + 1;                      // NB
    int* counts    = btot + NB;                            // NC*NB (cbase after scan)
    __half* W1t    = (__half*)(counts + (size_t)NC * NB);  // 128*128 f16
    __half* W2t    = W1t + 128 * 128;                      // 64*128 f16

    // --- atomic-free CSR build (bscan folded into scatter; convert in tail) ---
    k_prep<<<NC + 96, 256, 0, stream>>>(dst, counts, W1, W2, W1t, W2t, E, NB, NC);
    k_colscan<<<NB, 256, 0, stream>>>(counts, btot, NB, NC);
    k_scatter2<<<1024, 256, 0, stream>>>(src, dst, counts, btot, bstart, pairs,
                                         X, X16, E, NB, NC, (long long)N * 32);
    k_sort<<<NB, 256, 0, stream>>>(pairs, bstart, edge_src, row_start, N, E);

    // --- split layer-1: gather-agg at fabric floor, then fused GEMM1+GEMM2 ---
    k_agg1<<<(N * 16 + 255) / 256, 256, 0, stream>>>(X16, edge_src, row_start, agg1h, N);
    k_mgemm2<<<(N + 63) / 64, 256, 0, stream>>>(agg1h, W1t, b1, W2t, m2h, N);
    k_agg2<<<(N * 8 + 255) / 256, 256, 0, stream>>>(m2h, edge_src, row_start, b2, out, N);
}

// Round 22
// 174.798 us; speedup vs baseline: 1.0797x; 1.0797x over previous
//
#include <hip/hip_runtime.h>
#include <hip/hip_fp16.h>

// GCN: atomic-free two-level CSR build + single-wave fused gather+MFMA layer-1.
//   1) k_prep: per-chunk bucket hist -> counts[chunk][bucket] + W1t/W2t cvt
//   2) k_colscan: per-bucket exclusive prefix over chunks (in-place) + totals
//   3) k_scatter2: local scan of btot -> bstart (block 0 publishes); LDS cursors
//      = bstart+cbase; LDS-atomic rank; X->fp16 convert tail
//   4) k_sort: per-bucket LDS counting sort -> edge_src (dst-sorted), row_start
//   5) k_fused1: ONE WAVE per 16 rows: A-tile = fp16((1/deg)*sum X16[src])
//      gathered into 4KB swizzled LDS, then m2h = fp16( relu(A@W1+b1) @ W2 ).
//      1-wave blocks keep waves independently phased -> best gather duty cycle.
//   6) k_agg2: out[n] = (1/deg) * sum m2h[src] + b2     (8 lanes/node, 16 deep)
// Requires N <= 2^17. N = 100000 here.

constexpr int CAP = 3072;      // max edges/bucket on LDS sort fast path
constexpr int CHUNK = 8192;    // edges per scatter chunk

typedef _Float16 f16x8 __attribute__((ext_vector_type(8)));
typedef float f32x4 __attribute__((ext_vector_type(4)));

// blocks < NC: hist of chunk -> counts[c][b] (coalesced store, no atomics)
// blocks NC..NC+95: W transposes.
__global__ __launch_bounds__(256) void k_prep(
    const int* __restrict__ dst, int* __restrict__ counts,
    const float* __restrict__ W1, const float* __restrict__ W2,
    __half* __restrict__ W1t, __half* __restrict__ W2t,
    int E, int NB, int NC)
{
    __shared__ int sh[1024];
    const int tid = threadIdx.x;
    if (blockIdx.x < NC) {
        const int c = blockIdx.x;
        const int b0 = c * CHUNK;
        const int cnt = min(CHUNK, E - b0);
        for (int i = tid; i < NB; i += 256) sh[i] = 0;
        __syncthreads();
        for (int i = tid; i < cnt; i += 256)
            atomicAdd(&sh[dst[b0 + i] >> 7], 1);
        __syncthreads();
        for (int i = tid; i < NB; i += 256) counts[(size_t)c * NB + i] = sh[i];
    } else {
        const int t = (blockIdx.x - NC) * 256 + tid;   // < 24576 exactly
        if (t < 128 * 128) {
            const int k = t >> 7, n = t & 127;
            W1t[n * 128 + k] = __float2half(W1[t]);
        } else {
            const int u = t - 128 * 128;
            const int k = u >> 6, n = u & 63;
            W2t[n * 128 + k] = __float2half(W2[u]);
        }
    }
}

// One block per bucket: exclusive prefix of counts[*][b] over chunks (in-place),
// totals -> btot[b].
__global__ __launch_bounds__(256) void k_colscan(
    int* __restrict__ counts, int* __restrict__ btot, int NB, int NC)
{
    __shared__ int sh[256];
    const int b = blockIdx.x;
    const int tid = threadIdx.x;
    int carry = 0;
    for (int t0 = 0; t0 < NC; t0 += 256) {
        const int idx = t0 + tid;
        const int v = (idx < NC) ? counts[(size_t)idx * NB + b] : 0;
        sh[tid] = v;
        __syncthreads();
        for (int off = 1; off < 256; off <<= 1) {
            int u = (tid >= off) ? sh[tid - off] : 0;
            __syncthreads();
            if (tid >= off) sh[tid] += u;
            __syncthreads();
        }
        const int incl = sh[tid];
        const int tile_total = sh[255];
        if (idx < NC) counts[(size_t)idx * NB + b] = incl - v + carry;
        carry += tile_total;
        __syncthreads();   // sh reused next tile
    }
    if (tid == 0) btot[b] = carry;
}

// Blocks < NC: local exclusive scan of btot -> bstartL (block 0 publishes to
// global bstart for k_sort); cursors = bstartL + cbase; LDS-atomic rank;
// scatter into block-private bucket windows. ALL blocks: X->fp16 convert tail.
__global__ __launch_bounds__(256) void k_scatter2(
    const int* __restrict__ src, const int* __restrict__ dst,
    const int* __restrict__ cbase, const int* __restrict__ btot,
    int* __restrict__ bstart_out, unsigned* __restrict__ pairs,
    const float* __restrict__ X, __half* __restrict__ X16,
    int E, int NB, int NC, long long n4)
{
    __shared__ int cur[1024];
    __shared__ int part[256];
    const int c = blockIdx.x;
    const int tid = threadIdx.x;

    if (c < NC) {
        // local exclusive scan of btot[0..NB) into cur[0..1023]
        int v[4];
        int run = 0;
#pragma unroll
        for (int q = 0; q < 4; ++q) {
            const int idx = tid * 4 + q;
            const int t = (idx < NB) ? btot[idx] : 0;
            v[q] = run;
            run += t;
        }
        part[tid] = run;
        __syncthreads();
        for (int off = 1; off < 256; off <<= 1) {
            int u = (tid >= off) ? part[tid - off] : 0;
            __syncthreads();
            if (tid >= off) part[tid] += u;
            __syncthreads();
        }
        const int excl = part[tid] - run;
#pragma unroll
        for (int q = 0; q < 4; ++q) cur[tid * 4 + q] = v[q] + excl;
        __syncthreads();

        if (c == 0) {
            for (int i = tid; i < NB; i += 256) bstart_out[i] = cur[i];
            if (tid == 0) bstart_out[NB] = E;
        }

        // cursors = bstartL + per-chunk base
        for (int i = tid; i < NB; i += 256)
            cur[i] += cbase[(size_t)c * NB + i];
        __syncthreads();

        const int b0 = c * CHUNK;
        const int cnt = min(CHUNK, E - b0);
        int i = tid;
        for (; i + 768 < cnt; i += 1024) {
            const int d0 = dst[b0 + i], s0 = src[b0 + i];
            const int d1 = dst[b0 + i + 256], s1 = src[b0 + i + 256];
            const int d2 = dst[b0 + i + 512], s2 = src[b0 + i + 512];
            const int d3 = dst[b0 + i + 768], s3 = src[b0 + i + 768];
            const int p0 = atomicAdd(&cur[d0 >> 7], 1);
            const int p1 = atomicAdd(&cur[d1 >> 7], 1);
            const int p2 = atomicAdd(&cur[d2 >> 7], 1);
            const int p3 = atomicAdd(&cur[d3 >> 7], 1);
            pairs[p0] = (unsigned)s0 | ((unsigned)(d0 & 127) << 17);
            pairs[p1] = (unsigned)s1 | ((unsigned)(d1 & 127) << 17);
            pairs[p2] = (unsigned)s2 | ((unsigned)(d2 & 127) << 17);
            pairs[p3] = (unsigned)s3 | ((unsigned)(d3 & 127) << 17);
        }
        for (; i < cnt; i += 256) {
            const int d = dst[b0 + i];
            const int p = atomicAdd(&cur[d >> 7], 1);
            pairs[p] = (unsigned)src[b0 + i] | ((unsigned)(d & 127) << 17);
        }
    }

    // X -> fp16 convert tail (all blocks). Consumed by k_fused1 (after k_sort).
    for (long long i = (long long)blockIdx.x * 256 + tid; i < n4;
         i += (long long)gridDim.x * 256) {
        const float4 v = ((const float4*)X)[i];
        __half2 h0 = __floats2half2_rn(v.x, v.y);
        __half2 h1 = __floats2half2_rn(v.z, v.w);
        uint2 o;
        o.x = *(const unsigned*)&h0;
        o.y = *(const unsigned*)&h1;
        ((uint2*)X16)[i] = o;
    }
}

__global__ __launch_bounds__(256) void k_sort(
    const unsigned* __restrict__ pairs, const int* __restrict__ bstart,
    int* __restrict__ edge_src, int* __restrict__ row_start, int N, int E)
{
    __shared__ unsigned sp[CAP];
    __shared__ int sorted[CAP];
    __shared__ int lcnt[128];
    __shared__ int ls[128];
    const int b = blockIdx.x;
    const int tid = threadIdx.x;
    const int beg = bstart[b], end = bstart[b + 1];
    const int cnt = end - beg;
    const bool fits = (cnt <= CAP);

    if (tid < 128) lcnt[tid] = 0;
    __syncthreads();

    if (fits) {
        for (int i = tid; i < cnt; i += 256) {
            const unsigned p = pairs[beg + i];
            sp[i] = p;
            atomicAdd(&lcnt[p >> 17], 1);
        }
    } else {
        for (int i = tid; i < cnt; i += 256)
            atomicAdd(&lcnt[pairs[beg + i] >> 17], 1);
    }
    __syncthreads();

    if (tid < 128) ls[tid] = lcnt[tid];
    __syncthreads();
    for (int off = 1; off < 128; off <<= 1) {
        int v = 0;
        if (tid < 128 && tid >= off) v = ls[tid - off];
        __syncthreads();
        if (tid < 128 && tid >= off) ls[tid] += v;
        __syncthreads();
    }

    if (tid < 128) {
        const int node = b * 128 + tid;
        if (node <= N) row_start[node] = beg + ls[tid] - lcnt[tid];
    }
    if (b == 0 && tid == 0) row_start[N] = E;
    __syncthreads();

    if (tid < 128) ls[tid] -= lcnt[tid];
    __syncthreads();

    if (fits) {
        for (int i = tid; i < cnt; i += 256) {
            const unsigned p = sp[i];
            const int pos = atomicAdd(&ls[p >> 17], 1);
            sorted[pos] = (int)(p & 0x1FFFFu);
        }
        __syncthreads();
        for (int i = tid; i < cnt; i += 256) edge_src[beg + i] = sorted[i];
    } else {
        for (int i = tid; i < cnt; i += 256) {
            const unsigned p = pairs[beg + i];
            const int pos = atomicAdd(&ls[p >> 17], 1);
            edge_src[beg + pos] = (int)(p & 0x1FFFFu);
        }
    }
}

// Single-wave fused layer-1: 64 threads, 16 rows/block. Gather-aggregate the
// A tile into 4KB swizzled LDS (16 lanes/node, 8 gathers in flight), GEMM1
// (+bias,relu) into the SAME 4KB (barrier-fenced), GEMM2, m2 bounce, copy-out.
// 1-wave blocks: barriers are cheap, waves stay independently phased.
__global__ __launch_bounds__(64) void k_fused1(
    const __half* __restrict__ X16, const int* __restrict__ edge_src,
    const int* __restrict__ row_start, const __half* __restrict__ W1t,
    const float* __restrict__ b1, const __half* __restrict__ W2t,
    __half* __restrict__ C, int N)
{
    __shared__ __align__(16) char lds[4096];
    const int tid = threadIdx.x;
    const int row0 = blockIdx.x * 16;
    const uint4* M4 = (const uint4*)X16;   // 16 uint4 per 128-ch row

    // phase 0: gather-aggregate A tile (16 x 128 fp16) into swizzled LDS
#pragma unroll
    for (int pass = 0; pass < 4; ++pass) {
        const int r = pass * 4 + (tid >> 4);
        const unsigned ch = tid & 15;
        const int row = row0 + r;
        float acc[8] = {};
        if (row < N) {
            const int beg = row_start[row];
            const int end = row_start[row + 1];
            const float inv = 1.0f / fmaxf((float)(end - beg), 1.0f);
            int j = beg;
            for (; j + 7 < end; j += 8) {
                unsigned o[8];
#pragma unroll
                for (int q = 0; q < 8; ++q)
                    o[q] = ((unsigned)edge_src[j + q] << 4) | ch;
                uint4 v[8];
#pragma unroll
                for (int q = 0; q < 8; ++q) v[q] = M4[o[q]];
#pragma unroll
                for (int q = 0; q < 8; ++q) {
                    const __half2* h = (const __half2*)&v[q];
#pragma unroll
                    for (int p = 0; p < 4; ++p) {
                        const float2 f = __half22float2(h[p]);
                        acc[2 * p] += f.x;
                        acc[2 * p + 1] += f.y;
                    }
                }
            }
            for (; j < end; ++j) {
                const uint4 v = M4[((unsigned)edge_src[j] << 4) | ch];
                const __half2* h = (const __half2*)&v;
#pragma unroll
                for (int p = 0; p < 4; ++p) {
                    const float2 f = __half22float2(h[p]);
                    acc[2 * p] += f.x;
                    acc[2 * p + 1] += f.y;
                }
            }
#pragma unroll
            for (int q = 0; q < 8; ++q) acc[q] *= inv;
        }
        __half2 rr[4];
#pragma unroll
        for (int p = 0; p < 4; ++p)
            rr[p] = __floats2half2_rn(acc[2 * p], acc[2 * p + 1]);
        *(uint4*)(lds + r * 256 + ((ch * 16) ^ ((r & 7) << 4))) = *(const uint4*)rr;
    }
    __syncthreads();   // fence: A-tile writes ordered before GEMM reads

    const int lr = tid & 15, lk = tid >> 4;

    // phase 2: GEMM1 (16 rows x 128 cols), A from LDS
    f32x4 acc1[8] = {};
#pragma unroll
    for (int kb = 0; kb < 4; ++kb) {
        const f16x8 a = *(const f16x8*)(lds + lr * 256 +
                                        ((kb * 64 + lk * 16) ^ ((lr & 7) << 4)));
#pragma unroll
        for (int nt = 0; nt < 8; ++nt) {
            const f16x8 b = *(const f16x8*)(W1t + (nt * 16 + lr) * 128 + kb * 32 + lk * 8);
            acc1[nt] = __builtin_amdgcn_mfma_f32_16x16x32_f16(a, b, acc1[nt], 0, 0, 0);
        }
    }
    __syncthreads();   // fence: A reads done before h overwrites the region

    // phase 3: h tile (16 x 128 fp16, bias+relu) -> same 4KB LDS region
#pragma unroll
    for (int nt = 0; nt < 8; ++nt) {
        const int col = nt * 16 + lr;
        const float bv = b1[col];
#pragma unroll
        for (int i = 0; i < 4; ++i) {
            const int r = lk * 4 + i;
            const float v = fmaxf(acc1[nt][i] + bv, 0.f);
            *(__half*)(lds + r * 256 + ((col * 2) ^ ((r & 7) << 4))) = __float2half(v);
        }
    }
    __syncthreads();   // fence: h writes ordered before a2 reads

    // phase 4: GEMM2 from LDS h
    f32x4 acc2[4] = {};
#pragma unroll
    for (int kb = 0; kb < 4; ++kb) {
        const f16x8 a2 = *(const f16x8*)(lds + lr * 256 +
                                         ((kb * 64 + lk * 16) ^ ((lr & 7) << 4)));
#pragma unroll
        for (int nt = 0; nt < 4; ++nt) {
            const f16x8 b = *(const f16x8*)(W2t + (nt * 16 + lr) * 128 + kb * 32 + lk * 8);
            acc2[nt] = __builtin_amdgcn_mfma_f32_16x16x32_f16(a2, b, acc2[nt], 0, 0, 0);
        }
    }
    __syncthreads();   // fence: a2 reads done before m2 overwrites the region

    // phase 5: m2 tile (16 x 64 fp16) bounce into the same region
#pragma unroll
    for (int nt = 0; nt < 4; ++nt) {
        const int col = nt * 16 + lr;
#pragma unroll
        for (int i = 0; i < 4; ++i) {
            const int r = lk * 4 + i;
            *(__half*)(lds + r * 128 + ((col * 2) ^ ((r & 7) << 4))) = __float2half(acc2[nt][i]);
        }
    }
    __syncthreads();   // fence: m2 writes ordered before copy-out reads

    // phase 6: coalesced copy-out (16 rows x 64 fp16 = 128 x 16B chunks)
    for (int i = tid; i < 128; i += 64) {
        const int r = i >> 3, c = i & 7;
        const int row = row0 + r;
        if (row < N)
            *(uint4*)(C + (size_t)row * 64 + c * 8) =
                *(const uint4*)(lds + r * 128 + ((c * 16) ^ ((r & 7) << 4)));
    }
}

// Layer-2 agg: 8 lanes per node (8 nodes/wave), 16 edges in flight per group.
// f32 out with 1/deg and bias fused.
__global__ __launch_bounds__(256) void k_agg2(
    const __half* __restrict__ M, const int* __restrict__ edge_src,
    const int* __restrict__ row_start, const float* __restrict__ bias,
    float* __restrict__ outp, int N)
{
    const int node = (blockIdx.x * 256 + threadIdx.x) >> 3;
    if (node >= N) return;
    const unsigned li = threadIdx.x & 7;
    const int beg = row_start[node];
    const int end = row_start[node + 1];
    const float inv = 1.0f / fmaxf((float)(end - beg), 1.0f);
    const uint4* M4 = (const uint4*)M;   // 8 uint4 per row

    float acc[8] = {};
    int j = beg;
    for (; j + 15 < end; j += 16) {
        unsigned o[16];
#pragma unroll
        for (int q = 0; q < 16; ++q)
            o[q] = ((unsigned)edge_src[j + q] << 3) | li;
        uint4 v[16];
#pragma unroll
        for (int q = 0; q < 16; ++q) v[q] = M4[o[q]];
#pragma unroll
        for (int q = 0; q < 16; ++q) {
            const __half2* h = (const __half2*)&v[q];
#pragma unroll
            for (int p = 0; p < 4; ++p) {
                const float2 f = __half22float2(h[p]);
                acc[2 * p] += f.x;
                acc[2 * p + 1] += f.y;
            }
        }
    }
    for (; j + 3 < end; j += 4) {
        unsigned o[4];
#pragma unroll
        for (int q = 0; q < 4; ++q)
            o[q] = ((unsigned)edge_src[j + q] << 3) | li;
        uint4 v[4];
#pragma unroll
        for (int q = 0; q < 4; ++q) v[q] = M4[o[q]];
#pragma unroll
        for (int q = 0; q < 4; ++q) {
            const __half2* h = (const __half2*)&v[q];
#pragma unroll
            for (int p = 0; p < 4; ++p) {
                const float2 f = __half22float2(h[p]);
                acc[2 * p] += f.x;
                acc[2 * p + 1] += f.y;
            }
        }
    }
    for (; j < end; ++j) {
        const uint4 v = M4[((unsigned)edge_src[j] << 3) | li];
        const __half2* h = (const __half2*)&v;
#pragma unroll
        for (int p = 0; p < 4; ++p) {
            const float2 f = __half22float2(h[p]);
            acc[2 * p] += f.x;
            acc[2 * p + 1] += f.y;
        }
    }
    const float4 b0 = ((const float4*)bias)[li * 2];
    const float4 b1 = ((const float4*)bias)[li * 2 + 1];
    float4 o0, o1;
    o0.x = fmaf(acc[0], inv, b0.x);
    o0.y = fmaf(acc[1], inv, b0.y);
    o0.z = fmaf(acc[2], inv, b0.z);
    o0.w = fmaf(acc[3], inv, b0.w);
    o1.x = fmaf(acc[4], inv, b1.x);
    o1.y = fmaf(acc[5], inv, b1.y);
    o1.z = fmaf(acc[6], inv, b1.z);
    o1.w = fmaf(acc[7], inv, b1.w);
    float4* op = (float4*)(outp + (size_t)node * 64);
    op[li * 2] = o0;
    op[li * 2 + 1] = o1;
}

extern "C" void kernel_launch(void* const* d_in, const int* in_sizes, int n_in,
                              void* d_out, int out_size, void* d_ws, size_t ws_size,
                              hipStream_t stream)
{
    const float* X  = (const float*)d_in[0];
    const int*  src = (const int*)d_in[1];
    const int*  dst = (const int*)d_in[2];
    const float* W1 = (const float*)d_in[3];
    const float* b1 = (const float*)d_in[4];
    const float* W2 = (const float*)d_in[5];
    const float* b2 = (const float*)d_in[6];
    float* out = (float*)d_out;

    const int N = in_sizes[0] / 128;
    const int E = in_sizes[1];
    const int NB = (N + 127) / 128;
    const int NC = (E + CHUNK - 1) / CHUNK;

    __half* X16    = (__half*)d_ws;                        // N*128 f16
    __half* m2h    = X16 + (size_t)N * 128;                // N*64 f16 (no alias)
    unsigned* pairs = (unsigned*)(m2h + (size_t)N * 64);   // E u32
    int* edge_src  = (int*)(pairs + E);                    // E
    int* row_start = edge_src + E;                         // N+1
    int* bstart    = row_start + N + 1;                    // NB+1
    int* btot      = bstart + NB + 1;                      // NB
    int* counts    = btot + NB;                            // NC*NB (cbase after scan)
    __half* W1t    = (__half*)(counts + (size_t)NC * NB);  // 128*128 f16
    __half* W2t    = W1t + 128 * 128;                      // 64*128 f16

    // --- atomic-free CSR build (bscan folded into scatter; convert in tail) ---
    k_prep<<<NC + 96, 256, 0, stream>>>(dst, counts, W1, W2, W1t, W2t, E, NB, NC);
    k_colscan<<<NB, 256, 0, stream>>>(counts, btot, NB, NC);
    k_scatter2<<<1024, 256, 0, stream>>>(src, dst, counts, btot, bstart, pairs,
                                         X, X16, E, NB, NC, (long long)N * 32);
    k_sort<<<NB, 256, 0, stream>>>(pairs, bstart, edge_src, row_start, N, E);

    // --- single-wave fused layer-1 (gather + GEMM1 + GEMM2), then layer-2 agg ---
    k_fused1<<<(N + 15) / 16, 64, 0, stream>>>(X16, edge_src, row_start,
                                               W1t, b1, W2t, m2h, N);
    k_agg2<<<(N * 8 + 255) / 256, 256, 0, stream>>>(m2h, edge_src, row_start, b2, out, N);
}